// Round 3
// baseline (303.648 us; speedup 1.0000x reference)
//
#include <hip/hip_runtime.h>
#include <stdint.h>

#define T_TOK 2048
#define H_DIM 1024
#define E_NUM 16
#define I_DIM 1024
#define TOTAL_ROWS (2 * T_TOK)   // exactly T*K assignment rows
#define CPAD 16                  // counts padded to one per 64B cacheline

typedef short bf16x8 __attribute__((ext_vector_type(8)));
typedef float f32x4 __attribute__((ext_vector_type(4)));

__device__ __forceinline__ void async_copy16(const void* g, void* l) {
  __builtin_amdgcn_global_load_lds(
      (const __attribute__((address_space(1))) void*)g,
      (__attribute__((address_space(3))) void*)l, 16, 0, 0);
}

// fp32 -> bf16 round-to-nearest-even (inputs finite)
__device__ __forceinline__ uint32_t f2bf(float f) {
  uint32_t u = __float_as_uint(f);
  return (u + 0x7FFFu + ((u >> 16) & 1u)) >> 16;
}
__device__ __forceinline__ uint32_t pk2bf(float lo, float hi) {
  return f2bf(lo) | (f2bf(hi) << 16);
}

// ---------------------------------------------------------------------------
// Workspace layout (bytes). Primary path needs ~108 MB; launcher falls back
// to the fp32-weight kernels if ws_size is smaller.
// ---------------------------------------------------------------------------
#define WS_COUNTS 0
#define WS_OFFSETS 2048
#define WS_TOKENS 4096
#define WS_WTS (4096 + 131072)
#define WS_XBF (4096 + 262144)
#define WS_HBUF (WS_XBF + 4194304)       // 4 MiB xbf
#define WS_GBUF (WS_HBUF + 8388608)      // 8 MiB hbuf
#define WS_UBUF (WS_GBUF + 33554432)     // 32 MiB gate bf16 tiles
#define WS_DBUF (WS_UBUF + 33554432)     // 32 MiB up bf16 tiles
#define WS_NEED (WS_DBUF + 33554432)     // 32 MiB down bf16 tiles

// ---------------------------------------------------------------------------
// Kernel 1 (merged): blocks [0,512) = router (fp32 exact, wave-per-token);
// blocks [512, 512+12288) = weight fp32->bf16 conversion into pre-swizzled
// 64x64 tile layout: tile(e,nt,kt) is 512 contiguous 16B chunks, chunk c
// holds source (row m=c>>3, col-chunk kq=(c&7)^(m&7)) — exactly the LDS
// image the GEMMs staged in R2, so the gemm fragment-read addressing is
// unchanged and B staging becomes pure global_load_lds (no VALU, no fp32
// latency chain in the K-loop). Conversion is pure-BW (~290 MB ≈ 48 µs).
// ---------------------------------------------------------------------------
__global__ __launch_bounds__(256) void router_prep_kernel(
    const float* __restrict__ x, const float* __restrict__ rw,
    const float* __restrict__ gate, const float* __restrict__ up,
    const float* __restrict__ down, uint16_t* __restrict__ xbf,
    int* __restrict__ counts, int* __restrict__ tokens,
    float* __restrict__ wts, uint16_t* __restrict__ gbuf,
    uint16_t* __restrict__ ubuf, uint16_t* __restrict__ dbuf) {
  const int bid = blockIdx.x;
  const int tid = threadIdx.x;

  if (bid < 512) {
    // ---- router: one wave per token ----
    const int t = bid * 4 + (tid >> 6);
    const int lane = tid & 63;

    float4 xv[4];
    float acc[E_NUM];
#pragma unroll
    for (int e = 0; e < E_NUM; ++e) acc[e] = 0.f;

#pragma unroll
    for (int rep = 0; rep < 4; ++rep) {
      const int h0 = rep * 256 + lane * 4;
      xv[rep] = *(const float4*)(x + (size_t)t * H_DIM + h0);
      uint2 p;
      p.x = pk2bf(xv[rep].x, xv[rep].y);
      p.y = pk2bf(xv[rep].z, xv[rep].w);
      *(uint2*)(xbf + (size_t)t * H_DIM + h0) = p;
    }

#pragma unroll
    for (int e = 0; e < E_NUM; ++e) {
#pragma unroll
      for (int rep = 0; rep < 4; ++rep) {
        const float4 rv =
            *(const float4*)(rw + (size_t)e * H_DIM + rep * 256 + lane * 4);
        acc[e] += xv[rep].x * rv.x + xv[rep].y * rv.y + xv[rep].z * rv.z +
                  xv[rep].w * rv.w;
      }
    }

#pragma unroll
    for (int e = 0; e < E_NUM; ++e) {
      float v = acc[e];
#pragma unroll
      for (int off = 32; off > 0; off >>= 1) v += __shfl_xor(v, off);
      acc[e] = v;
    }

    if (lane < 2) {
      float s[E_NUM];
#pragma unroll
      for (int e = 0; e < E_NUM; ++e) s[e] = 1.f / (1.f + expf(-acc[e]));
      int i1 = 0;
      float v1 = s[0];
#pragma unroll
      for (int e = 1; e < E_NUM; ++e)
        if (s[e] > v1) { v1 = s[e]; i1 = e; }
      int i2 = -1;
      float v2 = -1.f;
#pragma unroll
      for (int e = 0; e < E_NUM; ++e)
        if (e != i1 && s[e] > v2) { v2 = s[e]; i2 = e; }
      const float inv = 1.f / (v1 + v2 + 1e-20f);
      const int pe = (lane == 0) ? i1 : i2;
      const float pw = ((lane == 0) ? v1 : v2) * inv;
      const int slot = atomicAdd(&counts[pe * CPAD], 1);
      tokens[pe * T_TOK + slot] = t;
      wts[pe * T_TOK + slot] = pw;
    }
    return;
  }

  // ---- weight conversion: one 64x64 tile per block ----
  const int tt = bid - 512;        // 0 .. 12287
  const int mat = tt >> 12;        // 0=gate 1=up 2=down (4096 tiles each)
  const int r = tt & 4095;
  const int e = r >> 8;            // 16 experts
  const int nt = (r >> 4) & 15;    // 16 n-tiles
  const int kt = r & 15;           // 16 k-tiles
  const float* W = (mat == 0) ? gate : (mat == 1) ? up : down;
  uint16_t* D = (mat == 0) ? gbuf : (mat == 1) ? ubuf : dbuf;
  const float* src = W + ((size_t)e * 1024 + (size_t)nt * 64) * 1024 + kt * 64;
  uint16_t* dst = D + ((size_t)((e * 16 + nt) * 16 + kt)) * 4096;

#pragma unroll
  for (int h = 0; h < 2; ++h) {
    const int c = tid + h * 256;          // chunk 0..511
    const int m = c >> 3;                 // tile row
    const int kq = (c & 7) ^ (m & 7);     // swizzled col-chunk
    const float* s = src + (size_t)m * 1024 + kq * 8;
    const float4 a = *(const float4*)s;
    const float4 b = *(const float4*)(s + 4);
    uint4 p;
    p.x = pk2bf(a.x, a.y);
    p.y = pk2bf(a.z, a.w);
    p.z = pk2bf(b.x, b.y);
    p.w = pk2bf(b.z, b.w);
    *(uint4*)(dst + (size_t)c * 8) = p;
  }
}

// ---------------------------------------------------------------------------
// Kernel 2: exclusive prefix sum over the 16 (padded) expert counts.
// ---------------------------------------------------------------------------
__global__ void offsets_kernel(const int* __restrict__ counts,
                               int* __restrict__ offsets) {
  if (threadIdx.x == 0) {
    int a = 0;
    for (int e = 0; e < E_NUM; ++e) {
      offsets[e] = a;
      a += counts[e * CPAD];
    }
    offsets[E_NUM] = a;
  }
}

// ---------------------------------------------------------------------------
// R7 primary GEMMs: BM=128 BN=64 BK=64, 256 thr = 4 waves (each 32m x 64n),
// double-buffered LDS, ALL staging via global_load_lds (A token-gather, B
// linear from pre-tiled bf16). One __syncthreads per K-step; staging for
// tile t+1 is issued BEFORE computing tile t so the barrier's vmcnt(0)
// drain waits on loads that had a full compute phase (~32 MFMA + 20
// ds_read/wave) to land. Zero VALU conversion in the K-loop.
// gemm1 LDS 65.5KB -> 2 blocks/CU; gemm2 49KB -> 3 blocks/CU.
// ---------------------------------------------------------------------------
__global__ __launch_bounds__(256, 2) void gemm1_kernel(
    const uint16_t* __restrict__ xbf, const uint16_t* __restrict__ gbuf,
    const uint16_t* __restrict__ ubuf, const int* __restrict__ counts,
    const int* __restrict__ offsets, const int* __restrict__ tokens,
    const float* __restrict__ wts, uint16_t* __restrict__ hbuf) {
  const int e = blockIdx.z;
  const int count = counts[e * CPAD];
  const int m0 = blockIdx.y * 128;
  if (m0 >= count) return;
  const int n0t = blockIdx.x;  // n-tile index; n0 = n0t*64

  __shared__ __align__(16) uint16_t As[2][128 * 64];  // 32 KB
  __shared__ __align__(16) uint16_t Bgs[2][64 * 64];  // 16 KB
  __shared__ __align__(16) uint16_t Bus[2][64 * 64];  // 16 KB
  __shared__ int tok_s[128];
  __shared__ float wt_s[128];

  const int tid = threadIdx.x;
  if (tid < 128) {
    const int slot = m0 + tid;
    int tk = 0;
    float w = 0.f;
    if (slot < count) {
      tk = tokens[e * T_TOK + slot];
      w = wts[e * T_TOK + slot];
    }
    tok_s[tid] = tk;
    wt_s[tid] = w;
  }
  __syncthreads();

  // A: 1024 chunks, 4/thread (token-gather rows, swizzled col-chunk)
  const uint16_t* a_g[4];
  int a_c[4];
#pragma unroll
  for (int j = 0; j < 4; ++j) {
    const int c = j * 256 + tid;
    const int m = c >> 3;
    const int kq = (c & 7) ^ (m & 7);
    a_g[j] = xbf + (size_t)tok_s[m] * H_DIM + kq * 8;
    a_c[j] = c * 8;
  }
  // B: pre-tiled; K-step kt is 4096 contiguous elems. 2 chunks/thread/matrix.
  const uint16_t* g_g = gbuf + (size_t)((e * 16 + n0t) * 16) * 4096;
  const uint16_t* u_g = ubuf + (size_t)((e * 16 + n0t) * 16) * 4096;
  const int bc0 = tid * 8, bc1 = (tid + 256) * 8;

  const int wave = tid >> 6, lane = tid & 63;
  const int wm = wave * 32;
  const int lc = lane & 15, lq = lane >> 4;
  const int l7 = lc & 7;

  f32x4 accg[2][4], accu[2][4];
  const f32x4 zero4 = {0.f, 0.f, 0.f, 0.f};
#pragma unroll
  for (int i = 0; i < 2; ++i)
#pragma unroll
    for (int j = 0; j < 4; ++j) {
      accg[i][j] = zero4;
      accu[i][j] = zero4;
    }

  int am[2], bn[4];
#pragma unroll
  for (int i = 0; i < 2; ++i) am[i] = (wm + i * 16 + lc) * 64;
#pragma unroll
  for (int i = 0; i < 4; ++i) bn[i] = (i * 16 + lc) * 64;

  // ---- prologue: stage tile 0 into buf 0 ----
#pragma unroll
  for (int j = 0; j < 4; ++j) async_copy16(a_g[j], &As[0][a_c[j]]);
  async_copy16(g_g + bc0, &Bgs[0][bc0]);
  async_copy16(g_g + bc1, &Bgs[0][bc1]);
  async_copy16(u_g + bc0, &Bus[0][bc0]);
  async_copy16(u_g + bc1, &Bus[0][bc1]);
  __syncthreads();

  int cur = 0;
  for (int kt = 0; kt < 16; ++kt) {
    const bool more = (kt < 15);
    if (more) {
      const int ko = (kt + 1) * 64;        // A element offset
      const int bo = (kt + 1) * 4096;      // B element offset
      const int nb = cur ^ 1;
#pragma unroll
      for (int j = 0; j < 4; ++j) async_copy16(a_g[j] + ko, &As[nb][a_c[j]]);
      async_copy16(g_g + bo + bc0, &Bgs[nb][bc0]);
      async_copy16(g_g + bo + bc1, &Bgs[nb][bc1]);
      async_copy16(u_g + bo + bc0, &Bus[nb][bc0]);
      async_copy16(u_g + bo + bc1, &Bus[nb][bc1]);
    }

#pragma unroll
    for (int ks = 0; ks < 2; ++ks) {
      const int kswz = ((ks * 4 + lq) ^ l7) * 8;
      bf16x8 af[2], bg[4], bu[4];
#pragma unroll
      for (int i = 0; i < 2; ++i)
        af[i] = *(const bf16x8*)&As[cur][am[i] + kswz];
#pragma unroll
      for (int i = 0; i < 4; ++i) {
        bg[i] = *(const bf16x8*)&Bgs[cur][bn[i] + kswz];
        bu[i] = *(const bf16x8*)&Bus[cur][bn[i] + kswz];
      }
#pragma unroll
      for (int im = 0; im < 2; ++im)
#pragma unroll
        for (int in = 0; in < 4; ++in) {
          accg[im][in] = __builtin_amdgcn_mfma_f32_16x16x32_bf16(
              af[im], bg[in], accg[im][in], 0, 0, 0);
          accu[im][in] = __builtin_amdgcn_mfma_f32_16x16x32_bf16(
              af[im], bu[in], accu[im][in], 0, 0, 0);
        }
    }

    if (more) {
      __syncthreads();  // drain: staged loads had the full MFMA phase
      cur ^= 1;
    }
  }

  const int off_e = offsets[e];
#pragma unroll
  for (int im = 0; im < 2; ++im) {
#pragma unroll
    for (int r = 0; r < 4; ++r) {
      const int row = wm + im * 16 + lq * 4 + r;  // C/D: row=(lane>>4)*4+reg
      const int slot = m0 + row;
      if (slot < count) {
        const float w = wt_s[row];
        uint16_t* hrow = hbuf + (size_t)(off_e + slot) * I_DIM + n0t * 64;
#pragma unroll
        for (int in = 0; in < 4; ++in) {
          const float g = accg[im][in][r];
          const float u = accu[im][in][r];
          const float hv = g / (1.f + __expf(-g)) * u * w;
          hrow[in * 16 + lc] = (uint16_t)f2bf(hv);  // C/D: col=lane&15
        }
      }
    }
  }
}

__global__ __launch_bounds__(256, 3) void gemm2_kernel(
    const uint16_t* __restrict__ hbuf, const uint16_t* __restrict__ dbuf,
    const int* __restrict__ counts, const int* __restrict__ offsets,
    const int* __restrict__ tokens, float* __restrict__ out) {
  const int e = blockIdx.z;
  const int count = counts[e * CPAD];
  const int m0 = blockIdx.y * 128;
  if (m0 >= count) return;
  const int n0t = blockIdx.x;

  __shared__ __align__(16) uint16_t As[2][128 * 64];  // 32 KB
  __shared__ __align__(16) uint16_t Bs[2][64 * 64];   // 16 KB
  __shared__ int tok_s[128];

  const int tid = threadIdx.x;
  const int off_e = offsets[e];
  if (tid < 128) {
    const int slot = m0 + tid;
    tok_s[tid] = (slot < count) ? tokens[e * T_TOK + slot] : 0;
  }

  const uint16_t* a_g[4];
  int a_c[4];
#pragma unroll
  for (int j = 0; j < 4; ++j) {
    const int c = j * 256 + tid;
    const int m = c >> 3;
    const int kq = (c & 7) ^ (m & 7);
    int r = off_e + m0 + m;
    if (r > TOTAL_ROWS - 1) r = TOTAL_ROWS - 1;  // ragged tail: junk rows,
    a_g[j] = hbuf + (size_t)r * I_DIM + kq * 8;   // outputs masked below
    a_c[j] = c * 8;
  }
  const uint16_t* d_g = dbuf + (size_t)((e * 16 + n0t) * 16) * 4096;
  const int bc0 = tid * 8, bc1 = (tid + 256) * 8;

  const int wave = tid >> 6, lane = tid & 63;
  const int wm = wave * 32;
  const int lc = lane & 15, lq = lane >> 4;
  const int l7 = lc & 7;

  f32x4 acc[2][4];
  const f32x4 zero4 = {0.f, 0.f, 0.f, 0.f};
#pragma unroll
  for (int i = 0; i < 2; ++i)
#pragma unroll
    for (int j = 0; j < 4; ++j) acc[i][j] = zero4;

  int am[2], bn[4];
#pragma unroll
  for (int i = 0; i < 2; ++i) am[i] = (wm + i * 16 + lc) * 64;
#pragma unroll
  for (int i = 0; i < 4; ++i) bn[i] = (i * 16 + lc) * 64;

  __syncthreads();  // tok_s visible

#pragma unroll
  for (int j = 0; j < 4; ++j) async_copy16(a_g[j], &As[0][a_c[j]]);
  async_copy16(d_g + bc0, &Bs[0][bc0]);
  async_copy16(d_g + bc1, &Bs[0][bc1]);
  __syncthreads();

  int cur = 0;
  for (int kt = 0; kt < 16; ++kt) {
    const bool more = (kt < 15);
    if (more) {
      const int ko = (kt + 1) * 64;
      const int bo = (kt + 1) * 4096;
      const int nb = cur ^ 1;
#pragma unroll
      for (int j = 0; j < 4; ++j) async_copy16(a_g[j] + ko, &As[nb][a_c[j]]);
      async_copy16(d_g + bo + bc0, &Bs[nb][bc0]);
      async_copy16(d_g + bo + bc1, &Bs[nb][bc1]);
    }

#pragma unroll
    for (int ks = 0; ks < 2; ++ks) {
      const int kswz = ((ks * 4 + lq) ^ l7) * 8;
      bf16x8 af[2], bf[4];
#pragma unroll
      for (int i = 0; i < 2; ++i)
        af[i] = *(const bf16x8*)&As[cur][am[i] + kswz];
#pragma unroll
      for (int i = 0; i < 4; ++i)
        bf[i] = *(const bf16x8*)&Bs[cur][bn[i] + kswz];
#pragma unroll
      for (int im = 0; im < 2; ++im)
#pragma unroll
        for (int in = 0; in < 4; ++in)
          acc[im][in] = __builtin_amdgcn_mfma_f32_16x16x32_bf16(
              af[im], bf[in], acc[im][in], 0, 0, 0);
    }

    if (more) {
      __syncthreads();
      cur ^= 1;
    }
  }

#pragma unroll
  for (int im = 0; im < 2; ++im) {
#pragma unroll
    for (int r = 0; r < 4; ++r) {
      const int row = wm + im * 16 + lq * 4 + r;
      const int slot = m0 + row;
      if (slot < count) {
        float* orow = out + (size_t)tok_s[row] * H_DIM + n0t * 64;
#pragma unroll
        for (int in = 0; in < 4; ++in)
          atomicAdd(orow + in * 16 + lc, acc[im][in][r]);
      }
    }
  }
}

// ---------------------------------------------------------------------------
// Fallback GEMMs (fp32 weights, R2 structure) — used only if ws_size is too
// small for the bf16 weight buffers. Known-passing.
// ---------------------------------------------------------------------------
__global__ __launch_bounds__(256, 3) void gemm1_fb(
    const uint16_t* __restrict__ xbf, const float* __restrict__ gate,
    const float* __restrict__ up, const int* __restrict__ counts,
    const int* __restrict__ offsets, const int* __restrict__ tokens,
    const float* __restrict__ wts, uint16_t* __restrict__ hbuf) {
  const int e = blockIdx.z;
  const int count = counts[e * CPAD];
  const int m0 = blockIdx.y * 128;
  if (m0 >= count) return;
  const int n0 = blockIdx.x * 32;

  __shared__ __align__(16) uint16_t As[2][128 * 64];
  __shared__ __align__(16) uint16_t Bgs[2][32 * 64];
  __shared__ __align__(16) uint16_t Bus[2][32 * 64];
  __shared__ int tok_s[128];
  __shared__ float wt_s[128];

  const int tid = threadIdx.x;
  if (tid < 128) {
    const int slot = m0 + tid;
    int tk = 0;
    float w = 0.f;
    if (slot < count) {
      tk = tokens[e * T_TOK + slot];
      w = wts[e * T_TOK + slot];
    }
    tok_s[tid] = tk;
    wt_s[tid] = w;
  }
  __syncthreads();

  const uint16_t* a_g[4];
  int a_c[4];
#pragma unroll
  for (int j = 0; j < 4; ++j) {
    const int c = j * 256 + tid;
    const int m = c >> 3;
    const int kq = (c & 7) ^ (m & 7);
    a_g[j] = xbf + (size_t)tok_s[m] * H_DIM + kq * 8;
    a_c[j] = c * 8;
  }
  const int bm = tid >> 3;
  const int bkq = (tid & 7) ^ (bm & 7);
  const float* g_g = gate + ((size_t)e * I_DIM + n0 + bm) * H_DIM + bkq * 8;
  const float* u_g = up + ((size_t)e * I_DIM + n0 + bm) * H_DIM + bkq * 8;
  const int b_c = tid * 8;

  const int wave = tid >> 6, lane = tid & 63;
  const int wm = wave * 32;
  const int lc = lane & 15, lq = lane >> 4;
  const int l7 = lc & 7;

  f32x4 accg[2][2], accu[2][2];
  const f32x4 zero4 = {0.f, 0.f, 0.f, 0.f};
#pragma unroll
  for (int i = 0; i < 2; ++i)
#pragma unroll
    for (int j = 0; j < 2; ++j) {
      accg[i][j] = zero4;
      accu[i][j] = zero4;
    }

  int am[2], bn[2];
#pragma unroll
  for (int i = 0; i < 2; ++i) am[i] = (wm + i * 16 + lc) * 64;
#pragma unroll
  for (int i = 0; i < 2; ++i) bn[i] = (i * 16 + lc) * 64;

#pragma unroll
  for (int j = 0; j < 4; ++j) async_copy16(a_g[j], &As[0][a_c[j]]);
  float4 g0 = *(const float4*)g_g;
  float4 g1 = *(const float4*)(g_g + 4);
  float4 u0 = *(const float4*)u_g;
  float4 u1 = *(const float4*)(u_g + 4);
  {
    uint4 p;
    p.x = pk2bf(g0.x, g0.y);
    p.y = pk2bf(g0.z, g0.w);
    p.z = pk2bf(g1.x, g1.y);
    p.w = pk2bf(g1.z, g1.w);
    *(uint4*)&Bgs[0][b_c] = p;
    p.x = pk2bf(u0.x, u0.y);
    p.y = pk2bf(u0.z, u0.w);
    p.z = pk2bf(u1.x, u1.y);
    p.w = pk2bf(u1.z, u1.w);
    *(uint4*)&Bus[0][b_c] = p;
  }
  __syncthreads();

  int cur = 0;
  for (int k0 = 0; k0 < H_DIM; k0 += 64) {
    const int nxt = k0 + 64;
    const bool more = (nxt < H_DIM);
    if (more) {
#pragma unroll
      for (int j = 0; j < 4; ++j)
        async_copy16(a_g[j] + nxt, &As[cur ^ 1][a_c[j]]);
      g0 = *(const float4*)(g_g + nxt);
      g1 = *(const float4*)(g_g + nxt + 4);
      u0 = *(const float4*)(u_g + nxt);
      u1 = *(const float4*)(u_g + nxt + 4);
    }

#pragma unroll
    for (int ks = 0; ks < 2; ++ks) {
      const int kswz = ((ks * 4 + lq) ^ l7) * 8;
      bf16x8 af[2], bg[2], bu[2];
#pragma unroll
      for (int i = 0; i < 2; ++i)
        af[i] = *(const bf16x8*)&As[cur][am[i] + kswz];
#pragma unroll
      for (int i = 0; i < 2; ++i) {
        bg[i] = *(const bf16x8*)&Bgs[cur][bn[i] + kswz];
        bu[i] = *(const bf16x8*)&Bus[cur][bn[i] + kswz];
      }
#pragma unroll
      for (int im = 0; im < 2; ++im)
#pragma unroll
        for (int in = 0; in < 2; ++in) {
          accg[im][in] = __builtin_amdgcn_mfma_f32_16x16x32_bf16(
              af[im], bg[in], accg[im][in], 0, 0, 0);
          accu[im][in] = __builtin_amdgcn_mfma_f32_16x16x32_bf16(
              af[im], bu[in], accu[im][in], 0, 0, 0);
        }
    }

    if (more) {
      uint4 p;
      p.x = pk2bf(g0.x, g0.y);
      p.y = pk2bf(g0.z, g0.w);
      p.z = pk2bf(g1.x, g1.y);
      p.w = pk2bf(g1.z, g1.w);
      *(uint4*)&Bgs[cur ^ 1][b_c] = p;
      p.x = pk2bf(u0.x, u0.y);
      p.y = pk2bf(u0.z, u0.w);
      p.z = pk2bf(u1.x, u1.y);
      p.w = pk2bf(u1.z, u1.w);
      *(uint4*)&Bus[cur ^ 1][b_c] = p;
      __syncthreads();
      cur ^= 1;
    }
  }

  const int off_e = offsets[e];
#pragma unroll
  for (int im = 0; im < 2; ++im) {
#pragma unroll
    for (int r = 0; r < 4; ++r) {
      const int row = wm + im * 16 + lq * 4 + r;
      const int slot = m0 + row;
      if (slot < count) {
        const float w = wt_s[row];
        uint16_t* hrow = hbuf + (size_t)(off_e + slot) * I_DIM + n0;
#pragma unroll
        for (int in = 0; in < 2; ++in) {
          const float g = accg[im][in][r];
          const float u = accu[im][in][r];
          const float hv = g / (1.f + __expf(-g)) * u * w;
          hrow[in * 16 + lc] = (uint16_t)f2bf(hv);
        }
      }
    }
  }
}

__global__ __launch_bounds__(256, 3) void gemm2_fb(
    const uint16_t* __restrict__ hbuf, const float* __restrict__ down,
    const int* __restrict__ counts, const int* __restrict__ offsets,
    const int* __restrict__ tokens, float* __restrict__ out) {
  const int e = blockIdx.z;
  const int count = counts[e * CPAD];
  const int m0 = blockIdx.y * 128;
  if (m0 >= count) return;
  const int n0 = blockIdx.x * 32;

  __shared__ __align__(16) uint16_t As[2][128 * 64];
  __shared__ __align__(16) uint16_t Bs[2][32 * 64];
  __shared__ int tok_s[128];

  const int tid = threadIdx.x;
  const int off_e = offsets[e];
  if (tid < 128) {
    const int slot = m0 + tid;
    tok_s[tid] = (slot < count) ? tokens[e * T_TOK + slot] : 0;
  }

  const uint16_t* a_g[4];
  int a_c[4];
#pragma unroll
  for (int j = 0; j < 4; ++j) {
    const int c = j * 256 + tid;
    const int m = c >> 3;
    const int kq = (c & 7) ^ (m & 7);
    int r = off_e + m0 + m;
    if (r > TOTAL_ROWS - 1) r = TOTAL_ROWS - 1;
    a_g[j] = hbuf + (size_t)r * I_DIM + kq * 8;
    a_c[j] = c * 8;
  }
  const int bm = tid >> 3;
  const int bkq = (tid & 7) ^ (bm & 7);
  const float* d_g = down + ((size_t)e * H_DIM + n0 + bm) * I_DIM + bkq * 8;
  const int b_c = tid * 8;

  const int wave = tid >> 6, lane = tid & 63;
  const int wm = wave * 32;
  const int lc = lane & 15, lq = lane >> 4;
  const int l7 = lc & 7;

  f32x4 acc[2][2];
  const f32x4 zero4 = {0.f, 0.f, 0.f, 0.f};
#pragma unroll
  for (int i = 0; i < 2; ++i)
#pragma unroll
    for (int j = 0; j < 2; ++j) acc[i][j] = zero4;

  int am[2], bn[2];
#pragma unroll
  for (int i = 0; i < 2; ++i) am[i] = (wm + i * 16 + lc) * 64;
#pragma unroll
  for (int i = 0; i < 2; ++i) bn[i] = (i * 16 + lc) * 64;

#pragma unroll
  for (int j = 0; j < 4; ++j) async_copy16(a_g[j], &As[0][a_c[j]]);
  float4 d0 = *(const float4*)d_g;
  float4 d1 = *(const float4*)(d_g + 4);
  {
    uint4 p;
    p.x = pk2bf(d0.x, d0.y);
    p.y = pk2bf(d0.z, d0.w);
    p.z = pk2bf(d1.x, d1.y);
    p.w = pk2bf(d1.z, d1.w);
    *(uint4*)&Bs[0][b_c] = p;
  }
  __syncthreads();

  int cur = 0;
  for (int k0 = 0; k0 < I_DIM; k0 += 64) {
    const int nxt = k0 + 64;
    const bool more = (nxt < I_DIM);
    if (more) {
#pragma unroll
      for (int j = 0; j < 4; ++j)
        async_copy16(a_g[j] + nxt, &As[cur ^ 1][a_c[j]]);
      d0 = *(const float4*)(d_g + nxt);
      d1 = *(const float4*)(d_g + nxt + 4);
    }

#pragma unroll
    for (int ks = 0; ks < 2; ++ks) {
      const int kswz = ((ks * 4 + lq) ^ l7) * 8;
      bf16x8 af[2], bf[2];
#pragma unroll
      for (int i = 0; i < 2; ++i)
        af[i] = *(const bf16x8*)&As[cur][am[i] + kswz];
#pragma unroll
      for (int i = 0; i < 2; ++i)
        bf[i] = *(const bf16x8*)&Bs[cur][bn[i] + kswz];
#pragma unroll
      for (int im = 0; im < 2; ++im)
#pragma unroll
        for (int in = 0; in < 2; ++in)
          acc[im][in] = __builtin_amdgcn_mfma_f32_16x16x32_bf16(
              af[im], bf[in], acc[im][in], 0, 0, 0);
    }

    if (more) {
      uint4 p;
      p.x = pk2bf(d0.x, d0.y);
      p.y = pk2bf(d0.z, d0.w);
      p.z = pk2bf(d1.x, d1.y);
      p.w = pk2bf(d1.z, d1.w);
      *(uint4*)&Bs[cur ^ 1][b_c] = p;
      __syncthreads();
      cur ^= 1;
    }
  }

#pragma unroll
  for (int im = 0; im < 2; ++im) {
#pragma unroll
    for (int r = 0; r < 4; ++r) {
      const int row = wm + im * 16 + lq * 4 + r;
      const int slot = m0 + row;
      if (slot < count) {
        float* orow = out + (size_t)tok_s[row] * H_DIM + n0;
#pragma unroll
        for (int in = 0; in < 2; ++in)
          atomicAdd(orow + in * 16 + lc, acc[im][in][r]);
      }
    }
  }
}

// ---------------------------------------------------------------------------
extern "C" void kernel_launch(void* const* d_in, const int* in_sizes, int n_in,
                              void* d_out, int out_size, void* d_ws,
                              size_t ws_size, hipStream_t stream) {
  const float* x = (const float*)d_in[0];
  const float* rw = (const float*)d_in[1];
  const float* gate = (const float*)d_in[2];
  const float* up = (const float*)d_in[3];
  const float* down = (const float*)d_in[4];
  float* out = (float*)d_out;

  uint8_t* ws = (uint8_t*)d_ws;
  int* counts = (int*)(ws + WS_COUNTS);
  int* offsets = (int*)(ws + WS_OFFSETS);
  int* tokens = (int*)(ws + WS_TOKENS);
  float* wts = (float*)(ws + WS_WTS);
  uint16_t* xbf = (uint16_t*)(ws + WS_XBF);
  uint16_t* hbuf = (uint16_t*)(ws + WS_HBUF);
  uint16_t* gbuf = (uint16_t*)(ws + WS_GBUF);
  uint16_t* ubuf = (uint16_t*)(ws + WS_UBUF);
  uint16_t* dbuf = (uint16_t*)(ws + WS_DBUF);

  const bool big = (ws_size >= (size_t)WS_NEED);

  hipMemsetAsync(counts, 0, 2048, stream);
  hipMemsetAsync(out, 0, (size_t)out_size * sizeof(float), stream);

  if (big) {
    router_prep_kernel<<<512 + 12288, 256, 0, stream>>>(
        x, rw, gate, up, down, xbf, counts, tokens, wts, gbuf, ubuf, dbuf);
    offsets_kernel<<<1, 64, 0, stream>>>(counts, offsets);
    gemm1_kernel<<<dim3(16, 16, 16), 256, 0, stream>>>(
        xbf, gbuf, ubuf, counts, offsets, tokens, wts, hbuf);
    gemm2_kernel<<<dim3(16, 16, 16), 256, 0, stream>>>(hbuf, dbuf, counts,
                                                       offsets, tokens, out);
  } else {
    router_prep_kernel<<<512, 256, 0, stream>>>(
        x, rw, gate, up, down, xbf, counts, tokens, wts, gbuf, ubuf, dbuf);
    offsets_kernel<<<1, 64, 0, stream>>>(counts, offsets);
    gemm1_fb<<<dim3(32, 16, 16), 256, 0, stream>>>(
        xbf, gate, up, counts, offsets, tokens, wts, hbuf);
    gemm2_fb<<<dim3(32, 16, 16), 256, 0, stream>>>(hbuf, down, counts,
                                                   offsets, tokens, out);
  }
}

// Round 4
// 292.341 us; speedup vs baseline: 1.0387x; 1.0387x over previous
//
#include <hip/hip_runtime.h>
#include <stdint.h>

#define T_TOK 2048
#define H_DIM 1024
#define E_NUM 16
#define I_DIM 1024
#define TOTAL_ROWS (2 * T_TOK)   // exactly T*K assignment rows
#define CPAD 16                  // counts padded to one per 64B cacheline

typedef short bf16x8 __attribute__((ext_vector_type(8)));
typedef float f32x4 __attribute__((ext_vector_type(4)));

__device__ __forceinline__ void async_copy16(const void* g, void* l) {
  __builtin_amdgcn_global_load_lds(
      (const __attribute__((address_space(1))) void*)g,
      (__attribute__((address_space(3))) void*)l, 16, 0, 0);
}

// fp32 -> bf16 round-to-nearest-even (inputs finite)
__device__ __forceinline__ uint32_t f2bf(float f) {
  uint32_t u = __float_as_uint(f);
  return (u + 0x7FFFu + ((u >> 16) & 1u)) >> 16;
}
__device__ __forceinline__ uint32_t pk2bf(float lo, float hi) {
  return f2bf(lo) | (f2bf(hi) << 16);
}

// ---------------------------------------------------------------------------
// Workspace layout (bytes). Primary path needs ~108 MB; launcher falls back
// to the fp32-weight kernels if ws_size is smaller.
// ---------------------------------------------------------------------------
#define WS_COUNTS 0
#define WS_OFFSETS 2048
#define WS_TOKENS 4096
#define WS_WTS (4096 + 131072)
#define WS_XBF (4096 + 262144)
#define WS_HBUF (WS_XBF + 4194304)       // 4 MiB xbf
#define WS_GBUF (WS_HBUF + 8388608)      // 8 MiB hbuf
#define WS_UBUF (WS_GBUF + 33554432)     // 32 MiB gate bf16 tiles
#define WS_DBUF (WS_UBUF + 33554432)     // 32 MiB up bf16 tiles
#define WS_NEED (WS_DBUF + 33554432)     // 32 MiB down bf16 tiles

// ---------------------------------------------------------------------------
// Kernel 1 (merged): blocks [0,512) = router; blocks [512,512+12288) =
// weight fp32->bf16 conversion into pre-swizzled 64x64 tiles (tile(e,nt,kt)
// = 512 contiguous 16B chunks; chunk c holds src row m=c>>3, col-chunk
// kq=(c&7)^(m&7) — byte-identical to the GEMM LDS image).
// R8: all 4 global loads issued before any store (R3 interleaved them; the
// ternary-derived dst pointer loses restrict, so loads couldn't hoist past
// stores -> 2 serialized HBM round-trips/thread -> 2.4 TB/s).
// ---------------------------------------------------------------------------
__global__ __launch_bounds__(256) void router_prep_kernel(
    const float* __restrict__ x, const float* __restrict__ rw,
    const float* __restrict__ gate, const float* __restrict__ up,
    const float* __restrict__ down, uint16_t* __restrict__ xbf,
    int* __restrict__ counts, int* __restrict__ tokens,
    float* __restrict__ wts, uint16_t* __restrict__ gbuf,
    uint16_t* __restrict__ ubuf, uint16_t* __restrict__ dbuf) {
  const int bid = blockIdx.x;
  const int tid = threadIdx.x;

  if (bid < 512) {
    // ---- router: one wave per token ----
    const int t = bid * 4 + (tid >> 6);
    const int lane = tid & 63;

    float4 xv[4];
    float acc[E_NUM];
#pragma unroll
    for (int e = 0; e < E_NUM; ++e) acc[e] = 0.f;

#pragma unroll
    for (int rep = 0; rep < 4; ++rep) {
      const int h0 = rep * 256 + lane * 4;
      xv[rep] = *(const float4*)(x + (size_t)t * H_DIM + h0);
      uint2 p;
      p.x = pk2bf(xv[rep].x, xv[rep].y);
      p.y = pk2bf(xv[rep].z, xv[rep].w);
      *(uint2*)(xbf + (size_t)t * H_DIM + h0) = p;
    }

#pragma unroll
    for (int e = 0; e < E_NUM; ++e) {
#pragma unroll
      for (int rep = 0; rep < 4; ++rep) {
        const float4 rv =
            *(const float4*)(rw + (size_t)e * H_DIM + rep * 256 + lane * 4);
        acc[e] += xv[rep].x * rv.x + xv[rep].y * rv.y + xv[rep].z * rv.z +
                  xv[rep].w * rv.w;
      }
    }

#pragma unroll
    for (int e = 0; e < E_NUM; ++e) {
      float v = acc[e];
#pragma unroll
      for (int off = 32; off > 0; off >>= 1) v += __shfl_xor(v, off);
      acc[e] = v;
    }

    if (lane < 2) {
      float s[E_NUM];
#pragma unroll
      for (int e = 0; e < E_NUM; ++e) s[e] = 1.f / (1.f + expf(-acc[e]));
      int i1 = 0;
      float v1 = s[0];
#pragma unroll
      for (int e = 1; e < E_NUM; ++e)
        if (s[e] > v1) { v1 = s[e]; i1 = e; }
      int i2 = -1;
      float v2 = -1.f;
#pragma unroll
      for (int e = 0; e < E_NUM; ++e)
        if (e != i1 && s[e] > v2) { v2 = s[e]; i2 = e; }
      const float inv = 1.f / (v1 + v2 + 1e-20f);
      const int pe = (lane == 0) ? i1 : i2;
      const float pw = ((lane == 0) ? v1 : v2) * inv;
      const int slot = atomicAdd(&counts[pe * CPAD], 1);
      tokens[pe * T_TOK + slot] = t;
      wts[pe * T_TOK + slot] = pw;
    }
    return;
  }

  // ---- weight conversion: one 64x64 tile per block, loads-first ----
  const int tt = bid - 512;        // 0 .. 12287
  const int mat = tt >> 12;        // 0=gate 1=up 2=down (4096 tiles each)
  const int r = tt & 4095;
  const int e = r >> 8;            // 16 experts
  const int nt = (r >> 4) & 15;    // 16 n-tiles
  const int kt = r & 15;           // 16 k-tiles
  const float* W = (mat == 0) ? gate : (mat == 1) ? up : down;
  uint16_t* D = (mat == 0) ? gbuf : (mat == 1) ? ubuf : dbuf;
  const float* src = W + ((size_t)e * 1024 + (size_t)nt * 64) * 1024 + kt * 64;
  uint16_t* dst = D + ((size_t)((e * 16 + nt) * 16 + kt)) * 4096;

  const int c0 = tid;
  const int m0c = c0 >> 3, kq0 = (c0 & 7) ^ (m0c & 7);
  const int c1 = tid + 256;
  const int m1c = c1 >> 3, kq1 = (c1 & 7) ^ (m1c & 7);
  const float* s0 = src + (size_t)m0c * 1024 + kq0 * 8;
  const float* s1 = src + (size_t)m1c * 1024 + kq1 * 8;
  // all loads before any store (4x16B in flight per thread)
  const float4 a0 = *(const float4*)s0;
  const float4 b0 = *(const float4*)(s0 + 4);
  const float4 a1 = *(const float4*)s1;
  const float4 b1 = *(const float4*)(s1 + 4);
  uint4 p0, p1;
  p0.x = pk2bf(a0.x, a0.y);
  p0.y = pk2bf(a0.z, a0.w);
  p0.z = pk2bf(b0.x, b0.y);
  p0.w = pk2bf(b0.z, b0.w);
  p1.x = pk2bf(a1.x, a1.y);
  p1.y = pk2bf(a1.z, a1.w);
  p1.z = pk2bf(b1.x, b1.y);
  p1.w = pk2bf(b1.z, b1.w);
  *(uint4*)(dst + (size_t)c0 * 8) = p0;
  *(uint4*)(dst + (size_t)c1 * 8) = p1;
}

// ---------------------------------------------------------------------------
// Kernel 2: exclusive prefix sum over the 16 (padded) expert counts.
// ---------------------------------------------------------------------------
__global__ void offsets_kernel(const int* __restrict__ counts,
                               int* __restrict__ offsets) {
  if (threadIdx.x == 0) {
    int a = 0;
    for (int e = 0; e < E_NUM; ++e) {
      offsets[e] = a;
      a += counts[e * CPAD];
    }
    offsets[E_NUM] = a;
  }
}

// ---------------------------------------------------------------------------
// R8 GEMMs: counted-vmcnt pipeline (catalog T4). R3 post-mortem: my
// "2-phase" loop used __syncthreads() AFTER the stage-issue -> its implicit
// vmcnt(0) drained the just-issued loads every K-step (depth-0 pipeline,
// 16 exposed HBM latencies, 1.3 TB/s effective). New per-K-step:
//   issue stage(t+1 -> buf^1)            [8 (gemm1) / 6 (gemm2) vmem]
//   s_waitcnt vmcnt(8|6)                 <- waits stage(t), issued LAST iter
//   s_barrier (raw, no drain)            <- all waves' stage(t) landed
//   compute(buf)                         (ds_read+MFMA; lgkm auto-waited)
//   s_barrier (raw)                      <- nobody overwrites buf early
// Last iteration peeled with vmcnt(0). sched_barrier(0) fences keep the
// compiler from hoisting ds_reads above the wait (rule: inline-asm waits
// don't order register-consumers).
// ---------------------------------------------------------------------------
#define WAIT_VM(N)                                         \
  asm volatile("s_waitcnt vmcnt(" #N ")" ::: "memory");    \
  __builtin_amdgcn_s_barrier();                            \
  __builtin_amdgcn_sched_barrier(0);

#define TAIL_BAR()                                         \
  __builtin_amdgcn_sched_barrier(0);                       \
  __builtin_amdgcn_s_barrier();

__global__ __launch_bounds__(256, 2) void gemm1_kernel(
    const uint16_t* __restrict__ xbf, const uint16_t* __restrict__ gbuf,
    const uint16_t* __restrict__ ubuf, const int* __restrict__ counts,
    const int* __restrict__ offsets, const int* __restrict__ tokens,
    const float* __restrict__ wts, uint16_t* __restrict__ hbuf) {
  const int e = blockIdx.z;
  const int count = counts[e * CPAD];
  const int m0 = blockIdx.y * 128;
  if (m0 >= count) return;
  const int n0t = blockIdx.x;  // n-tile index; n0 = n0t*64

  __shared__ __align__(16) uint16_t As[2][128 * 64];  // 32 KB
  __shared__ __align__(16) uint16_t Bgs[2][64 * 64];  // 16 KB
  __shared__ __align__(16) uint16_t Bus[2][64 * 64];  // 16 KB
  __shared__ int tok_s[128];
  __shared__ float wt_s[128];

  const int tid = threadIdx.x;
  if (tid < 128) {
    const int slot = m0 + tid;
    int tk = 0;
    float w = 0.f;
    if (slot < count) {
      tk = tokens[e * T_TOK + slot];
      w = wts[e * T_TOK + slot];
    }
    tok_s[tid] = tk;
    wt_s[tid] = w;
  }
  __syncthreads();

  // A: 1024 chunks, 4/thread (token-gather rows, swizzled col-chunk)
  const uint16_t* a_g[4];
  int a_c[4];
#pragma unroll
  for (int j = 0; j < 4; ++j) {
    const int c = j * 256 + tid;
    const int m = c >> 3;
    const int kq = (c & 7) ^ (m & 7);
    a_g[j] = xbf + (size_t)tok_s[m] * H_DIM + kq * 8;
    a_c[j] = c * 8;
  }
  // B: pre-tiled; K-step kt is 4096 contiguous elems. 2 chunks/thread/matrix.
  const uint16_t* g_g = gbuf + (size_t)((e * 16 + n0t) * 16) * 4096;
  const uint16_t* u_g = ubuf + (size_t)((e * 16 + n0t) * 16) * 4096;
  const int bc0 = tid * 8, bc1 = (tid + 256) * 8;

  const int wave = tid >> 6, lane = tid & 63;
  const int wm = wave * 32;
  const int lc = lane & 15, lq = lane >> 4;
  const int l7 = lc & 7;

  f32x4 accg[2][4], accu[2][4];
  const f32x4 zero4 = {0.f, 0.f, 0.f, 0.f};
#pragma unroll
  for (int i = 0; i < 2; ++i)
#pragma unroll
    for (int j = 0; j < 4; ++j) {
      accg[i][j] = zero4;
      accu[i][j] = zero4;
    }

  int am[2], bn[4];
#pragma unroll
  for (int i = 0; i < 2; ++i) am[i] = (wm + i * 16 + lc) * 64;
#pragma unroll
  for (int i = 0; i < 4; ++i) bn[i] = (i * 16 + lc) * 64;

#define G1_STAGE(BUF, KT)                                                 \
  {                                                                       \
    const int ko_ = (KT)*64;                                              \
    const int bo_ = (KT)*4096;                                            \
    _Pragma("unroll") for (int j = 0; j < 4; ++j)                         \
        async_copy16(a_g[j] + ko_, &As[BUF][a_c[j]]);                     \
    async_copy16(g_g + bo_ + bc0, &Bgs[BUF][bc0]);                        \
    async_copy16(g_g + bo_ + bc1, &Bgs[BUF][bc1]);                        \
    async_copy16(u_g + bo_ + bc0, &Bus[BUF][bc0]);                        \
    async_copy16(u_g + bo_ + bc1, &Bus[BUF][bc1]);                        \
  }

#define G1_COMPUTE(CB)                                                    \
  _Pragma("unroll") for (int ks = 0; ks < 2; ++ks) {                      \
    const int kswz = ((ks * 4 + lq) ^ l7) * 8;                            \
    bf16x8 af[2], bg[4], bu[4];                                           \
    _Pragma("unroll") for (int i = 0; i < 2; ++i) af[i] =                 \
        *(const bf16x8*)&As[CB][am[i] + kswz];                            \
    _Pragma("unroll") for (int i = 0; i < 4; ++i) {                       \
      bg[i] = *(const bf16x8*)&Bgs[CB][bn[i] + kswz];                     \
      bu[i] = *(const bf16x8*)&Bus[CB][bn[i] + kswz];                     \
    }                                                                     \
    _Pragma("unroll") for (int im = 0; im < 2; ++im)                      \
        _Pragma("unroll") for (int in = 0; in < 4; ++in) {                \
      accg[im][in] = __builtin_amdgcn_mfma_f32_16x16x32_bf16(             \
          af[im], bg[in], accg[im][in], 0, 0, 0);                         \
      accu[im][in] = __builtin_amdgcn_mfma_f32_16x16x32_bf16(             \
          af[im], bu[in], accu[im][in], 0, 0, 0);                         \
    }                                                                     \
  }

  // prologue: stage tile 0
  G1_STAGE(0, 0)
  int cur = 0;
  for (int kt = 0; kt < 15; ++kt) {
    G1_STAGE(cur ^ 1, kt + 1)
    WAIT_VM(8)
    G1_COMPUTE(cur)
    TAIL_BAR()
    cur ^= 1;
  }
  WAIT_VM(0)
  G1_COMPUTE(cur)

  const int off_e = offsets[e];
#pragma unroll
  for (int im = 0; im < 2; ++im) {
#pragma unroll
    for (int r = 0; r < 4; ++r) {
      const int row = wm + im * 16 + lq * 4 + r;  // C/D: row=(lane>>4)*4+reg
      const int slot = m0 + row;
      if (slot < count) {
        const float w = wt_s[row];
        uint16_t* hrow = hbuf + (size_t)(off_e + slot) * I_DIM + n0t * 64;
#pragma unroll
        for (int in = 0; in < 4; ++in) {
          const float g = accg[im][in][r];
          const float u = accu[im][in][r];
          const float hv = g / (1.f + __expf(-g)) * u * w;
          hrow[in * 16 + lc] = (uint16_t)f2bf(hv);  // C/D: col=lane&15
        }
      }
    }
  }
}

__global__ __launch_bounds__(256, 3) void gemm2_kernel(
    const uint16_t* __restrict__ hbuf, const uint16_t* __restrict__ dbuf,
    const int* __restrict__ counts, const int* __restrict__ offsets,
    const int* __restrict__ tokens, float* __restrict__ out) {
  const int e = blockIdx.z;
  const int count = counts[e * CPAD];
  const int m0 = blockIdx.y * 128;
  if (m0 >= count) return;
  const int n0t = blockIdx.x;

  __shared__ __align__(16) uint16_t As[2][128 * 64];  // 32 KB
  __shared__ __align__(16) uint16_t Bs[2][64 * 64];   // 16 KB
  __shared__ int tok_s[128];

  const int tid = threadIdx.x;
  const int off_e = offsets[e];
  if (tid < 128) {
    const int slot = m0 + tid;
    tok_s[tid] = (slot < count) ? tokens[e * T_TOK + slot] : 0;
  }

  const uint16_t* a_g[4];
  int a_c[4];
#pragma unroll
  for (int j = 0; j < 4; ++j) {
    const int c = j * 256 + tid;
    const int m = c >> 3;
    const int kq = (c & 7) ^ (m & 7);
    int r = off_e + m0 + m;
    if (r > TOTAL_ROWS - 1) r = TOTAL_ROWS - 1;  // ragged tail: junk rows,
    a_g[j] = hbuf + (size_t)r * I_DIM + kq * 8;   // outputs masked below
    a_c[j] = c * 8;
  }
  const uint16_t* d_g = dbuf + (size_t)((e * 16 + n0t) * 16) * 4096;
  const int bc0 = tid * 8, bc1 = (tid + 256) * 8;

  const int wave = tid >> 6, lane = tid & 63;
  const int wm = wave * 32;
  const int lc = lane & 15, lq = lane >> 4;
  const int l7 = lc & 7;

  f32x4 acc[2][4];
  const f32x4 zero4 = {0.f, 0.f, 0.f, 0.f};
#pragma unroll
  for (int i = 0; i < 2; ++i)
#pragma unroll
    for (int j = 0; j < 4; ++j) acc[i][j] = zero4;

  int am[2], bn[4];
#pragma unroll
  for (int i = 0; i < 2; ++i) am[i] = (wm + i * 16 + lc) * 64;
#pragma unroll
  for (int i = 0; i < 4; ++i) bn[i] = (i * 16 + lc) * 64;

  __syncthreads();  // tok_s visible

#define G2_STAGE(BUF, KT)                                                 \
  {                                                                       \
    const int ko_ = (KT)*64;                                              \
    const int bo_ = (KT)*4096;                                            \
    _Pragma("unroll") for (int j = 0; j < 4; ++j)                         \
        async_copy16(a_g[j] + ko_, &As[BUF][a_c[j]]);                     \
    async_copy16(d_g + bo_ + bc0, &Bs[BUF][bc0]);                         \
    async_copy16(d_g + bo_ + bc1, &Bs[BUF][bc1]);                         \
  }

#define G2_COMPUTE(CB)                                                    \
  _Pragma("unroll") for (int ks = 0; ks < 2; ++ks) {                      \
    const int kswz = ((ks * 4 + lq) ^ l7) * 8;                            \
    bf16x8 af[2], bf[4];                                                  \
    _Pragma("unroll") for (int i = 0; i < 2; ++i) af[i] =                 \
        *(const bf16x8*)&As[CB][am[i] + kswz];                            \
    _Pragma("unroll") for (int i = 0; i < 4; ++i) bf[i] =                 \
        *(const bf16x8*)&Bs[CB][bn[i] + kswz];                            \
    _Pragma("unroll") for (int im = 0; im < 2; ++im)                      \
        _Pragma("unroll") for (int in = 0; in < 4; ++in) acc[im][in] =    \
            __builtin_amdgcn_mfma_f32_16x16x32_bf16(af[im], bf[in],       \
                                                    acc[im][in], 0, 0, 0);\
  }

  G2_STAGE(0, 0)
  int cur = 0;
  for (int kt = 0; kt < 15; ++kt) {
    G2_STAGE(cur ^ 1, kt + 1)
    WAIT_VM(6)
    G2_COMPUTE(cur)
    TAIL_BAR()
    cur ^= 1;
  }
  WAIT_VM(0)
  G2_COMPUTE(cur)

#pragma unroll
  for (int im = 0; im < 2; ++im) {
#pragma unroll
    for (int r = 0; r < 4; ++r) {
      const int row = wm + im * 16 + lq * 4 + r;
      const int slot = m0 + row;
      if (slot < count) {
        float* orow = out + (size_t)tok_s[row] * H_DIM + n0t * 64;
#pragma unroll
        for (int in = 0; in < 4; ++in)
          atomicAdd(orow + in * 16 + lc, acc[im][in][r]);
      }
    }
  }
}

// ---------------------------------------------------------------------------
// Fallback GEMMs (fp32 weights, R2 structure) — used only if ws_size is too
// small for the bf16 weight buffers. Known-passing.
// ---------------------------------------------------------------------------
__global__ __launch_bounds__(256, 3) void gemm1_fb(
    const uint16_t* __restrict__ xbf, const float* __restrict__ gate,
    const float* __restrict__ up, const int* __restrict__ counts,
    const int* __restrict__ offsets, const int* __restrict__ tokens,
    const float* __restrict__ wts, uint16_t* __restrict__ hbuf) {
  const int e = blockIdx.z;
  const int count = counts[e * CPAD];
  const int m0 = blockIdx.y * 128;
  if (m0 >= count) return;
  const int n0 = blockIdx.x * 32;

  __shared__ __align__(16) uint16_t As[2][128 * 64];
  __shared__ __align__(16) uint16_t Bgs[2][32 * 64];
  __shared__ __align__(16) uint16_t Bus[2][32 * 64];
  __shared__ int tok_s[128];
  __shared__ float wt_s[128];

  const int tid = threadIdx.x;
  if (tid < 128) {
    const int slot = m0 + tid;
    int tk = 0;
    float w = 0.f;
    if (slot < count) {
      tk = tokens[e * T_TOK + slot];
      w = wts[e * T_TOK + slot];
    }
    tok_s[tid] = tk;
    wt_s[tid] = w;
  }
  __syncthreads();

  const uint16_t* a_g[4];
  int a_c[4];
#pragma unroll
  for (int j = 0; j < 4; ++j) {
    const int c = j * 256 + tid;
    const int m = c >> 3;
    const int kq = (c & 7) ^ (m & 7);
    a_g[j] = xbf + (size_t)tok_s[m] * H_DIM + kq * 8;
    a_c[j] = c * 8;
  }
  const int bm = tid >> 3;
  const int bkq = (tid & 7) ^ (bm & 7);
  const float* g_g = gate + ((size_t)e * I_DIM + n0 + bm) * H_DIM + bkq * 8;
  const float* u_g = up + ((size_t)e * I_DIM + n0 + bm) * H_DIM + bkq * 8;
  const int b_c = tid * 8;

  const int wave = tid >> 6, lane = tid & 63;
  const int wm = wave * 32;
  const int lc = lane & 15, lq = lane >> 4;
  const int l7 = lc & 7;

  f32x4 accg[2][2], accu[2][2];
  const f32x4 zero4 = {0.f, 0.f, 0.f, 0.f};
#pragma unroll
  for (int i = 0; i < 2; ++i)
#pragma unroll
    for (int j = 0; j < 2; ++j) {
      accg[i][j] = zero4;
      accu[i][j] = zero4;
    }

  int am[2], bn[2];
#pragma unroll
  for (int i = 0; i < 2; ++i) am[i] = (wm + i * 16 + lc) * 64;
#pragma unroll
  for (int i = 0; i < 2; ++i) bn[i] = (i * 16 + lc) * 64;

#pragma unroll
  for (int j = 0; j < 4; ++j) async_copy16(a_g[j], &As[0][a_c[j]]);
  float4 g0 = *(const float4*)g_g;
  float4 g1 = *(const float4*)(g_g + 4);
  float4 u0 = *(const float4*)u_g;
  float4 u1 = *(const float4*)(u_g + 4);
  {
    uint4 p;
    p.x = pk2bf(g0.x, g0.y);
    p.y = pk2bf(g0.z, g0.w);
    p.z = pk2bf(g1.x, g1.y);
    p.w = pk2bf(g1.z, g1.w);
    *(uint4*)&Bgs[0][b_c] = p;
    p.x = pk2bf(u0.x, u0.y);
    p.y = pk2bf(u0.z, u0.w);
    p.z = pk2bf(u1.x, u1.y);
    p.w = pk2bf(u1.z, u1.w);
    *(uint4*)&Bus[0][b_c] = p;
  }
  __syncthreads();

  int cur = 0;
  for (int k0 = 0; k0 < H_DIM; k0 += 64) {
    const int nxt = k0 + 64;
    const bool more = (nxt < H_DIM);
    if (more) {
#pragma unroll
      for (int j = 0; j < 4; ++j)
        async_copy16(a_g[j] + nxt, &As[cur ^ 1][a_c[j]]);
      g0 = *(const float4*)(g_g + nxt);
      g1 = *(const float4*)(g_g + nxt + 4);
      u0 = *(const float4*)(u_g + nxt);
      u1 = *(const float4*)(u_g + nxt + 4);
    }

#pragma unroll
    for (int ks = 0; ks < 2; ++ks) {
      const int kswz = ((ks * 4 + lq) ^ l7) * 8;
      bf16x8 af[2], bg[2], bu[2];
#pragma unroll
      for (int i = 0; i < 2; ++i)
        af[i] = *(const bf16x8*)&As[cur][am[i] + kswz];
#pragma unroll
      for (int i = 0; i < 2; ++i) {
        bg[i] = *(const bf16x8*)&Bgs[cur][bn[i] + kswz];
        bu[i] = *(const bf16x8*)&Bus[cur][bn[i] + kswz];
      }
#pragma unroll
      for (int im = 0; im < 2; ++im)
#pragma unroll
        for (int in = 0; in < 2; ++in) {
          accg[im][in] = __builtin_amdgcn_mfma_f32_16x16x32_bf16(
              af[im], bg[in], accg[im][in], 0, 0, 0);
          accu[im][in] = __builtin_amdgcn_mfma_f32_16x16x32_bf16(
              af[im], bu[in], accu[im][in], 0, 0, 0);
        }
    }

    if (more) {
      uint4 p;
      p.x = pk2bf(g0.x, g0.y);
      p.y = pk2bf(g0.z, g0.w);
      p.z = pk2bf(g1.x, g1.y);
      p.w = pk2bf(g1.z, g1.w);
      *(uint4*)&Bgs[cur ^ 1][b_c] = p;
      p.x = pk2bf(u0.x, u0.y);
      p.y = pk2bf(u0.z, u0.w);
      p.z = pk2bf(u1.x, u1.y);
      p.w = pk2bf(u1.z, u1.w);
      *(uint4*)&Bus[cur ^ 1][b_c] = p;
      __syncthreads();
      cur ^= 1;
    }
  }

  const int off_e = offsets[e];
#pragma unroll
  for (int im = 0; im < 2; ++im) {
#pragma unroll
    for (int r = 0; r < 4; ++r) {
      const int row = wm + im * 16 + lq * 4 + r;
      const int slot = m0 + row;
      if (slot < count) {
        const float w = wt_s[row];
        uint16_t* hrow = hbuf + (size_t)(off_e + slot) * I_DIM + n0;
#pragma unroll
        for (int in = 0; in < 2; ++in) {
          const float g = accg[im][in][r];
          const float u = accu[im][in][r];
          const float hv = g / (1.f + __expf(-g)) * u * w;
          hrow[in * 16 + lc] = (uint16_t)f2bf(hv);
        }
      }
    }
  }
}

__global__ __launch_bounds__(256, 3) void gemm2_fb(
    const uint16_t* __restrict__ hbuf, const float* __restrict__ down,
    const int* __restrict__ counts, const int* __restrict__ offsets,
    const int* __restrict__ tokens, float* __restrict__ out) {
  const int e = blockIdx.z;
  const int count = counts[e * CPAD];
  const int m0 = blockIdx.y * 128;
  if (m0 >= count) return;
  const int n0 = blockIdx.x * 32;

  __shared__ __align__(16) uint16_t As[2][128 * 64];
  __shared__ __align__(16) uint16_t Bs[2][32 * 64];
  __shared__ int tok_s[128];

  const int tid = threadIdx.x;
  const int off_e = offsets[e];
  if (tid < 128) {
    const int slot = m0 + tid;
    tok_s[tid] = (slot < count) ? tokens[e * T_TOK + slot] : 0;
  }

  const uint16_t* a_g[4];
  int a_c[4];
#pragma unroll
  for (int j = 0; j < 4; ++j) {
    const int c = j * 256 + tid;
    const int m = c >> 3;
    const int kq = (c & 7) ^ (m & 7);
    int r = off_e + m0 + m;
    if (r > TOTAL_ROWS - 1) r = TOTAL_ROWS - 1;
    a_g[j] = hbuf + (size_t)r * I_DIM + kq * 8;
    a_c[j] = c * 8;
  }
  const int bm = tid >> 3;
  const int bkq = (tid & 7) ^ (bm & 7);
  const float* d_g = down + ((size_t)e * H_DIM + n0 + bm) * I_DIM + bkq * 8;
  const int b_c = tid * 8;

  const int wave = tid >> 6, lane = tid & 63;
  const int wm = wave * 32;
  const int lc = lane & 15, lq = lane >> 4;
  const int l7 = lc & 7;

  f32x4 acc[2][2];
  const f32x4 zero4 = {0.f, 0.f, 0.f, 0.f};
#pragma unroll
  for (int i = 0; i < 2; ++i)
#pragma unroll
    for (int j = 0; j < 2; ++j) acc[i][j] = zero4;

  int am[2], bn[2];
#pragma unroll
  for (int i = 0; i < 2; ++i) am[i] = (wm + i * 16 + lc) * 64;
#pragma unroll
  for (int i = 0; i < 2; ++i) bn[i] = (i * 16 + lc) * 64;

#pragma unroll
  for (int j = 0; j < 4; ++j) async_copy16(a_g[j], &As[0][a_c[j]]);
  float4 d0 = *(const float4*)d_g;
  float4 d1 = *(const float4*)(d_g + 4);
  {
    uint4 p;
    p.x = pk2bf(d0.x, d0.y);
    p.y = pk2bf(d0.z, d0.w);
    p.z = pk2bf(d1.x, d1.y);
    p.w = pk2bf(d1.z, d1.w);
    *(uint4*)&Bs[0][b_c] = p;
  }
  __syncthreads();

  int cur = 0;
  for (int k0 = 0; k0 < I_DIM; k0 += 64) {
    const int nxt = k0 + 64;
    const bool more = (nxt < I_DIM);
    if (more) {
#pragma unroll
      for (int j = 0; j < 4; ++j)
        async_copy16(a_g[j] + nxt, &As[cur ^ 1][a_c[j]]);
      d0 = *(const float4*)(d_g + nxt);
      d1 = *(const float4*)(d_g + nxt + 4);
    }

#pragma unroll
    for (int ks = 0; ks < 2; ++ks) {
      const int kswz = ((ks * 4 + lq) ^ l7) * 8;
      bf16x8 af[2], bf[2];
#pragma unroll
      for (int i = 0; i < 2; ++i)
        af[i] = *(const bf16x8*)&As[cur][am[i] + kswz];
#pragma unroll
      for (int i = 0; i < 2; ++i)
        bf[i] = *(const bf16x8*)&Bs[cur][bn[i] + kswz];
#pragma unroll
      for (int im = 0; im < 2; ++im)
#pragma unroll
        for (int in = 0; in < 2; ++in)
          acc[im][in] = __builtin_amdgcn_mfma_f32_16x16x32_bf16(
              af[im], bf[in], acc[im][in], 0, 0, 0);
    }

    if (more) {
      uint4 p;
      p.x = pk2bf(d0.x, d0.y);
      p.y = pk2bf(d0.z, d0.w);
      p.z = pk2bf(d1.x, d1.y);
      p.w = pk2bf(d1.z, d1.w);
      *(uint4*)&Bs[cur ^ 1][b_c] = p;
      __syncthreads();
      cur ^= 1;
    }
  }

#pragma unroll
  for (int im = 0; im < 2; ++im) {
#pragma unroll
    for (int r = 0; r < 4; ++r) {
      const int row = wm + im * 16 + lq * 4 + r;
      const int slot = m0 + row;
      if (slot < count) {
        float* orow = out + (size_t)tok_s[row] * H_DIM + n0;
#pragma unroll
        for (int in = 0; in < 2; ++in)
          atomicAdd(orow + in * 16 + lc, acc[im][in][r]);
      }
    }
  }
}

// ---------------------------------------------------------------------------
extern "C" void kernel_launch(void* const* d_in, const int* in_sizes, int n_in,
                              void* d_out, int out_size, void* d_ws,
                              size_t ws_size, hipStream_t stream) {
  const float* x = (const float*)d_in[0];
  const float* rw = (const float*)d_in[1];
  const float* gate = (const float*)d_in[2];
  const float* up = (const float*)d_in[3];
  const float* down = (const float*)d_in[4];
  float* out = (float*)d_out;

  uint8_t* ws = (uint8_t*)d_ws;
  int* counts = (int*)(ws + WS_COUNTS);
  int* offsets = (int*)(ws + WS_OFFSETS);
  int* tokens = (int*)(ws + WS_TOKENS);
  float* wts = (float*)(ws + WS_WTS);
  uint16_t* xbf = (uint16_t*)(ws + WS_XBF);
  uint16_t* hbuf = (uint16_t*)(ws + WS_HBUF);
  uint16_t* gbuf = (uint16_t*)(ws + WS_GBUF);
  uint16_t* ubuf = (uint16_t*)(ws + WS_UBUF);
  uint16_t* dbuf = (uint16_t*)(ws + WS_DBUF);

  const bool big = (ws_size >= (size_t)WS_NEED);

  hipMemsetAsync(counts, 0, 2048, stream);
  hipMemsetAsync(out, 0, (size_t)out_size * sizeof(float), stream);

  if (big) {
    router_prep_kernel<<<512 + 12288, 256, 0, stream>>>(
        x, rw, gate, up, down, xbf, counts, tokens, wts, gbuf, ubuf, dbuf);
    offsets_kernel<<<1, 64, 0, stream>>>(counts, offsets);
    gemm1_kernel<<<dim3(16, 16, 16), 256, 0, stream>>>(
        xbf, gbuf, ubuf, counts, offsets, tokens, wts, hbuf);
    gemm2_kernel<<<dim3(16, 16, 16), 256, 0, stream>>>(hbuf, dbuf, counts,
                                                       offsets, tokens, out);
  } else {
    router_prep_kernel<<<512, 256, 0, stream>>>(
        x, rw, gate, up, down, xbf, counts, tokens, wts, gbuf, ubuf, dbuf);
    offsets_kernel<<<1, 64, 0, stream>>>(counts, offsets);
    gemm1_fb<<<dim3(32, 16, 16), 256, 0, stream>>>(
        xbf, gate, up, counts, offsets, tokens, wts, hbuf);
    gemm2_fb<<<dim3(32, 16, 16), 256, 0, stream>>>(hbuf, down, counts,
                                                   offsets, tokens, out);
  }
}

// Round 7
// 280.035 us; speedup vs baseline: 1.0843x; 1.0439x over previous
//
#include <hip/hip_runtime.h>
#include <stdint.h>

#define T_TOK 2048
#define H_DIM 1024
#define E_NUM 16
#define I_DIM 1024
#define TOTAL_ROWS (2 * T_TOK)   // exactly T*K assignment rows
#define CPAD 16                  // counts padded to one per 64B cacheline

typedef short bf16x8 __attribute__((ext_vector_type(8)));
typedef float f32x4 __attribute__((ext_vector_type(4)));

__device__ __forceinline__ void async_copy16(const void* g, void* l) {
  __builtin_amdgcn_global_load_lds(
      (const __attribute__((address_space(1))) void*)g,
      (__attribute__((address_space(3))) void*)l, 16, 0, 0);
}

// fp32 -> bf16 round-to-nearest-even (inputs finite)
__device__ __forceinline__ uint32_t f2bf(float f) {
  uint32_t u = __float_as_uint(f);
  return (u + 0x7FFFu + ((u >> 16) & 1u)) >> 16;
}
__device__ __forceinline__ uint32_t pk2bf(float lo, float hi) {
  return f2bf(lo) | (f2bf(hi) << 16);
}

// ---------------------------------------------------------------------------
// Workspace layout (bytes). Total ~28.5 MB.
// ---------------------------------------------------------------------------
#define WS_COUNTS 0
#define WS_OFFSETS 2048
#define WS_ROWS 4096                     // 2048*2 ints: (expert,slot) per assignment
#define WS_TOKENS 20480                  // 128 KiB
#define WS_WTS 151552                    // 128 KiB
#define WS_XBF 294912                    // 4 MiB bf16 x
#define WS_HBUF (WS_XBF + 4194304)       // 8 MiB bf16 h
#define WS_OBUF (WS_HBUF + 8388608)      // 16 MiB fp32 per-assignment out

// ---------------------------------------------------------------------------
// Kernel 1: router (fp32 exact) + x -> bf16. Wave-per-token. Also records
// rows[t*2+k] = e*4096 + slot so the combine kernel can sum the two
// per-assignment output rows (replaces gemm2's 4.2M global atomicAdds).
// ---------------------------------------------------------------------------
__global__ __launch_bounds__(256) void router_kernel(
    const float* __restrict__ x, const float* __restrict__ rw,
    uint16_t* __restrict__ xbf, int* __restrict__ counts,
    int* __restrict__ tokens, float* __restrict__ wts,
    int* __restrict__ rows) {
  const int t = blockIdx.x * 4 + (threadIdx.x >> 6);
  const int lane = threadIdx.x & 63;

  float4 xv[4];
  float acc[E_NUM];
#pragma unroll
  for (int e = 0; e < E_NUM; ++e) acc[e] = 0.f;

#pragma unroll
  for (int rep = 0; rep < 4; ++rep) {
    const int h0 = rep * 256 + lane * 4;
    xv[rep] = *(const float4*)(x + (size_t)t * H_DIM + h0);
    uint2 p;
    p.x = pk2bf(xv[rep].x, xv[rep].y);
    p.y = pk2bf(xv[rep].z, xv[rep].w);
    *(uint2*)(xbf + (size_t)t * H_DIM + h0) = p;
  }

#pragma unroll
  for (int e = 0; e < E_NUM; ++e) {
#pragma unroll
    for (int rep = 0; rep < 4; ++rep) {
      const float4 rv =
          *(const float4*)(rw + (size_t)e * H_DIM + rep * 256 + lane * 4);
      acc[e] += xv[rep].x * rv.x + xv[rep].y * rv.y + xv[rep].z * rv.z +
                xv[rep].w * rv.w;
    }
  }

#pragma unroll
  for (int e = 0; e < E_NUM; ++e) {
    float v = acc[e];
#pragma unroll
    for (int off = 32; off > 0; off >>= 1) v += __shfl_xor(v, off);
    acc[e] = v;
  }

  if (lane < 2) {
    float s[E_NUM];
#pragma unroll
    for (int e = 0; e < E_NUM; ++e) s[e] = 1.f / (1.f + expf(-acc[e]));
    int i1 = 0;
    float v1 = s[0];
#pragma unroll
    for (int e = 1; e < E_NUM; ++e)
      if (s[e] > v1) { v1 = s[e]; i1 = e; }
    int i2 = -1;
    float v2 = -1.f;
#pragma unroll
    for (int e = 0; e < E_NUM; ++e)
      if (e != i1 && s[e] > v2) { v2 = s[e]; i2 = e; }
    const float inv = 1.f / (v1 + v2 + 1e-20f);
    const int pe = (lane == 0) ? i1 : i2;
    const float pw = ((lane == 0) ? v1 : v2) * inv;
    const int slot = atomicAdd(&counts[pe * CPAD], 1);
    tokens[pe * T_TOK + slot] = t;
    wts[pe * T_TOK + slot] = pw;
    rows[t * 2 + lane] = pe * 4096 + slot;
  }
}

// ---------------------------------------------------------------------------
// Kernel 2: exclusive prefix sum over the 16 (padded) expert counts.
// ---------------------------------------------------------------------------
__global__ void offsets_kernel(const int* __restrict__ counts,
                               int* __restrict__ offsets) {
  if (threadIdx.x == 0) {
    int a = 0;
    for (int e = 0; e < E_NUM; ++e) {
      offsets[e] = a;
      a += counts[e * CPAD];
    }
    offsets[E_NUM] = a;
  }
}

// ---------------------------------------------------------------------------
// R5 GEMMs (compile-fixed): fp32 weights read DIRECTLY. Counted-vmcnt
// pipeline, in-order vmem retirement:
//   iter t: issue A(t+1)[gload_lds] ; issue B(t+2)[->regs, 2-ahead dbuf]
//           compute(t)
//           vmcnt(NA+NB)  -> B(t+1) regs ready   (A(t+1),B(t+2) in flight)
//           convert B(t+1) -> LDS buf^1
//           vmcnt(NB) lgkmcnt(0) -> A(t+1) landed, ds_writes drained
//           s_barrier
// No vmcnt(0) in the loop. B reg double-buffer = float4 arrays with
// COMPILE-TIME-CONSTANT indices only (rule #20 safe; R6's name-pasting
// macros were an invalid-pp-token compile error).
// gemm1: NA=4 NB=8 -> waits 12/8.  gemm2: NA=4 NB=4 -> waits 8/4.
// ---------------------------------------------------------------------------
#define FENCE() __builtin_amdgcn_sched_barrier(0)

__global__ __launch_bounds__(256, 2) void gemm1_kernel(
    const uint16_t* __restrict__ xbf, const float* __restrict__ gate,
    const float* __restrict__ up, const int* __restrict__ counts,
    const int* __restrict__ offsets, const int* __restrict__ tokens,
    const float* __restrict__ wts, uint16_t* __restrict__ hbuf) {
  const int e = blockIdx.z;
  const int count = counts[e * CPAD];
  const int m0 = blockIdx.y * 128;
  if (m0 >= count) return;
  const int n0 = blockIdx.x * 64;

  __shared__ __align__(16) uint16_t As[2][128 * 64];  // 32 KB
  __shared__ __align__(16) uint16_t Bgs[2][64 * 64];  // 16 KB
  __shared__ __align__(16) uint16_t Bus[2][64 * 64];  // 16 KB
  __shared__ int tok_s[128];
  __shared__ float wt_s[128];

  const int tid = threadIdx.x;
  if (tid < 128) {
    const int slot = m0 + tid;
    int tk = 0;
    float w = 0.f;
    if (slot < count) {
      tk = tokens[e * T_TOK + slot];
      w = wts[e * T_TOK + slot];
    }
    tok_s[tid] = tk;
    wt_s[tid] = w;
  }
  __syncthreads();

  // A: 1024 16B chunks, 4/thread; swizzled SOURCE offset, linear LDS dest.
  const uint16_t* a_g[4];
  int a_c[4];
#pragma unroll
  for (int j = 0; j < 4; ++j) {
    const int c = j * 256 + tid;
    const int m = c >> 3;
    const int kq = (c & 7) ^ (m & 7);
    a_g[j] = xbf + (size_t)tok_s[m] * H_DIM + kq * 8;
    a_c[j] = c * 8;
  }
  // B: 512 chunks/matrix; thread owns chunks {tid, tid+256} of both.
  const int bm = tid >> 3;
  const int bkq = (tid & 7) ^ (bm & 7);
  const float* gp0 = gate + ((size_t)e * I_DIM + n0 + bm) * H_DIM + bkq * 8;
  const float* gp1 = gp0 + 32 * H_DIM;
  const float* uq0 = up + ((size_t)e * I_DIM + n0 + bm) * H_DIM + bkq * 8;
  const float* uq1 = uq0 + 32 * H_DIM;
  const int bc0 = tid * 8, bc1 = (tid + 256) * 8;

  const int wave = tid >> 6, lane = tid & 63;
  const int wm = wave * 32;
  const int lc = lane & 15, lq = lane >> 4;
  const int l7 = lc & 7;

  f32x4 accg[2][4], accu[2][4];
  const f32x4 zero4 = {0.f, 0.f, 0.f, 0.f};
#pragma unroll
  for (int i = 0; i < 2; ++i)
#pragma unroll
    for (int j = 0; j < 4; ++j) {
      accg[i][j] = zero4;
      accu[i][j] = zero4;
    }

  int am[2], bn[4];
#pragma unroll
  for (int i = 0; i < 2; ++i) am[i] = (wm + i * 16 + lc) * 64;
#pragma unroll
  for (int i = 0; i < 4; ++i) bn[i] = (i * 16 + lc) * 64;

  float4 bA[8];  // even-parity B regs (const-indexed only)
  float4 bB[8];  // odd-parity B regs

#define G1_STAGE(BUF, KT)                                                 \
  {                                                                       \
    const int ko_ = (KT)*64;                                              \
    _Pragma("unroll") for (int j = 0; j < 4; ++j)                         \
        async_copy16(a_g[j] + ko_, &As[BUF][a_c[j]]);                     \
  }

#define G1_LOADB(KT, v)                                                   \
  v[0] = *(const float4*)(gp0 + (KT)*64);                                 \
  v[1] = *(const float4*)(gp0 + (KT)*64 + 4);                             \
  v[2] = *(const float4*)(gp1 + (KT)*64);                                 \
  v[3] = *(const float4*)(gp1 + (KT)*64 + 4);                             \
  v[4] = *(const float4*)(uq0 + (KT)*64);                                 \
  v[5] = *(const float4*)(uq0 + (KT)*64 + 4);                             \
  v[6] = *(const float4*)(uq1 + (KT)*64);                                 \
  v[7] = *(const float4*)(uq1 + (KT)*64 + 4);

#define G1_WRITEB(BUF, v)                                                 \
  {                                                                       \
    uint4 p;                                                              \
    p.x = pk2bf(v[0].x, v[0].y); p.y = pk2bf(v[0].z, v[0].w);             \
    p.z = pk2bf(v[1].x, v[1].y); p.w = pk2bf(v[1].z, v[1].w);             \
    *(uint4*)&Bgs[BUF][bc0] = p;                                          \
    p.x = pk2bf(v[2].x, v[2].y); p.y = pk2bf(v[2].z, v[2].w);             \
    p.z = pk2bf(v[3].x, v[3].y); p.w = pk2bf(v[3].z, v[3].w);             \
    *(uint4*)&Bgs[BUF][bc1] = p;                                          \
    p.x = pk2bf(v[4].x, v[4].y); p.y = pk2bf(v[4].z, v[4].w);             \
    p.z = pk2bf(v[5].x, v[5].y); p.w = pk2bf(v[5].z, v[5].w);             \
    *(uint4*)&Bus[BUF][bc0] = p;                                          \
    p.x = pk2bf(v[6].x, v[6].y); p.y = pk2bf(v[6].z, v[6].w);             \
    p.z = pk2bf(v[7].x, v[7].y); p.w = pk2bf(v[7].z, v[7].w);             \
    *(uint4*)&Bus[BUF][bc1] = p;                                          \
  }

#define G1_COMPUTE(CB)                                                    \
  _Pragma("unroll") for (int ks = 0; ks < 2; ++ks) {                      \
    const int kswz = ((ks * 4 + lq) ^ l7) * 8;                            \
    bf16x8 af[2], bg[4], bu[4];                                           \
    _Pragma("unroll") for (int i = 0; i < 2; ++i) af[i] =                 \
        *(const bf16x8*)&As[CB][am[i] + kswz];                            \
    _Pragma("unroll") for (int i = 0; i < 4; ++i) {                       \
      bg[i] = *(const bf16x8*)&Bgs[CB][bn[i] + kswz];                     \
      bu[i] = *(const bf16x8*)&Bus[CB][bn[i] + kswz];                     \
    }                                                                     \
    _Pragma("unroll") for (int im = 0; im < 2; ++im)                      \
        _Pragma("unroll") for (int in = 0; in < 4; ++in) {                \
      accg[im][in] = __builtin_amdgcn_mfma_f32_16x16x32_bf16(             \
          af[im], bg[in], accg[im][in], 0, 0, 0);                         \
      accu[im][in] = __builtin_amdgcn_mfma_f32_16x16x32_bf16(             \
          af[im], bu[in], accu[im][in], 0, 0, 0);                         \
    }                                                                     \
  }

  // ---- prologue: A(0)->LDS, B(0)->bA, B(1)->bB; convert B(0) ----
  G1_STAGE(0, 0)
  G1_LOADB(0, bA)
  G1_LOADB(1, bB)
  asm volatile("s_waitcnt vmcnt(8)" ::: "memory");  // A(0)+B(0) done
  FENCE();
  G1_WRITEB(0, bA)
  asm volatile("s_waitcnt lgkmcnt(0)" ::: "memory");
  FENCE();
  __builtin_amdgcn_s_barrier();
  FENCE();

  int cur = 0;
#pragma unroll 1
  for (int t2 = 0; t2 < 7; ++t2) {
    const int t = t2 * 2;
    // even logical iter t: load B(t+2)->bA, convert B(t+1)=bB
    G1_STAGE(cur ^ 1, t + 1)
    G1_LOADB(t + 2, bA)
    G1_COMPUTE(cur)
    asm volatile("s_waitcnt vmcnt(12)" ::: "memory");  // B(t+1) regs ready
    FENCE();
    G1_WRITEB(cur ^ 1, bB)
    asm volatile("s_waitcnt vmcnt(8) lgkmcnt(0)" ::: "memory");  // A(t+1) in
    FENCE();
    __builtin_amdgcn_s_barrier();
    FENCE();
    cur ^= 1;
    // odd logical iter t+1: load B(t+3)->bB, convert B(t+2)=bA
    G1_STAGE(cur ^ 1, t + 2)
    G1_LOADB(t + 3, bB)
    G1_COMPUTE(cur)
    asm volatile("s_waitcnt vmcnt(12)" ::: "memory");
    FENCE();
    G1_WRITEB(cur ^ 1, bA)
    asm volatile("s_waitcnt vmcnt(8) lgkmcnt(0)" ::: "memory");
    FENCE();
    __builtin_amdgcn_s_barrier();
    FENCE();
    cur ^= 1;
  }
  // logical iter 14: stage A(15); convert B(15)=bB (loaded at iter 13)
  G1_STAGE(cur ^ 1, 15)
  G1_COMPUTE(cur)
  asm volatile("s_waitcnt vmcnt(4)" ::: "memory");  // B(15) done, A(15) left
  FENCE();
  G1_WRITEB(cur ^ 1, bB)
  asm volatile("s_waitcnt vmcnt(0) lgkmcnt(0)" ::: "memory");
  FENCE();
  __builtin_amdgcn_s_barrier();
  FENCE();
  cur ^= 1;
  // logical iter 15: compute only
  G1_COMPUTE(cur)

  const int off_e = offsets[e];
#pragma unroll
  for (int im = 0; im < 2; ++im) {
#pragma unroll
    for (int r = 0; r < 4; ++r) {
      const int row = wm + im * 16 + lq * 4 + r;  // C/D: row=(lane>>4)*4+reg
      const int slot = m0 + row;
      if (slot < count) {
        const float w = wt_s[row];
        uint16_t* hrow = hbuf + (size_t)(off_e + slot) * I_DIM + n0;
#pragma unroll
        for (int in = 0; in < 4; ++in) {
          const float g = accg[im][in][r];
          const float u = accu[im][in][r];
          const float hv = g / (1.f + __expf(-g)) * u * w;
          hrow[in * 16 + lc] = (uint16_t)f2bf(hv);  // C/D: col=lane&15
        }
      }
    }
  }
}

// ---------------------------------------------------------------------------
// Kernel 4: GEMM2  obuf[row] = h[row] @ down_wT  (plain stores; combine sums)
// ---------------------------------------------------------------------------
__global__ __launch_bounds__(256, 3) void gemm2_kernel(
    const uint16_t* __restrict__ hbuf, const float* __restrict__ down,
    const int* __restrict__ counts, const int* __restrict__ offsets,
    float* __restrict__ obuf) {
  const int e = blockIdx.z;
  const int count = counts[e * CPAD];
  const int m0 = blockIdx.y * 128;
  if (m0 >= count) return;
  const int n0 = blockIdx.x * 64;

  __shared__ __align__(16) uint16_t As[2][128 * 64];  // 32 KB
  __shared__ __align__(16) uint16_t Bs[2][64 * 64];   // 16 KB

  const int tid = threadIdx.x;
  const int off_e = offsets[e];

  const uint16_t* a_g[4];
  int a_c[4];
#pragma unroll
  for (int j = 0; j < 4; ++j) {
    const int c = j * 256 + tid;
    const int m = c >> 3;
    const int kq = (c & 7) ^ (m & 7);
    int r = off_e + m0 + m;
    if (r > TOTAL_ROWS - 1) r = TOTAL_ROWS - 1;  // ragged tail: junk rows,
    a_g[j] = hbuf + (size_t)r * I_DIM + kq * 8;   // outputs masked below
    a_c[j] = c * 8;
  }
  const int bm = tid >> 3;
  const int bkq = (tid & 7) ^ (bm & 7);
  const float* dp0 = down + ((size_t)e * H_DIM + n0 + bm) * I_DIM + bkq * 8;
  const float* dp1 = dp0 + 32 * I_DIM;
  const int bc0 = tid * 8, bc1 = (tid + 256) * 8;

  const int wave = tid >> 6, lane = tid & 63;
  const int wm = wave * 32;
  const int lc = lane & 15, lq = lane >> 4;
  const int l7 = lc & 7;

  f32x4 acc[2][4];
  const f32x4 zero4 = {0.f, 0.f, 0.f, 0.f};
#pragma unroll
  for (int i = 0; i < 2; ++i)
#pragma unroll
    for (int j = 0; j < 4; ++j) acc[i][j] = zero4;

  int am[2], bn[4];
#pragma unroll
  for (int i = 0; i < 2; ++i) am[i] = (wm + i * 16 + lc) * 64;
#pragma unroll
  for (int i = 0; i < 4; ++i) bn[i] = (i * 16 + lc) * 64;

  float4 dA[4];  // even-parity B regs (const-indexed only)
  float4 dB[4];  // odd-parity

#define G2_STAGE(BUF, KT)                                                 \
  {                                                                       \
    const int ko_ = (KT)*64;                                              \
    _Pragma("unroll") for (int j = 0; j < 4; ++j)                         \
        async_copy16(a_g[j] + ko_, &As[BUF][a_c[j]]);                     \
  }

#define G2_LOADB(KT, v)                                                   \
  v[0] = *(const float4*)(dp0 + (KT)*64);                                 \
  v[1] = *(const float4*)(dp0 + (KT)*64 + 4);                             \
  v[2] = *(const float4*)(dp1 + (KT)*64);                                 \
  v[3] = *(const float4*)(dp1 + (KT)*64 + 4);

#define G2_WRITEB(BUF, v)                                                 \
  {                                                                       \
    uint4 p;                                                              \
    p.x = pk2bf(v[0].x, v[0].y); p.y = pk2bf(v[0].z, v[0].w);             \
    p.z = pk2bf(v[1].x, v[1].y); p.w = pk2bf(v[1].z, v[1].w);             \
    *(uint4*)&Bs[BUF][bc0] = p;                                           \
    p.x = pk2bf(v[2].x, v[2].y); p.y = pk2bf(v[2].z, v[2].w);             \
    p.z = pk2bf(v[3].x, v[3].y); p.w = pk2bf(v[3].z, v[3].w);             \
    *(uint4*)&Bs[BUF][bc1] = p;                                           \
  }

#define G2_COMPUTE(CB)                                                    \
  _Pragma("unroll") for (int ks = 0; ks < 2; ++ks) {                      \
    const int kswz = ((ks * 4 + lq) ^ l7) * 8;                            \
    bf16x8 af[2], bf[4];                                                  \
    _Pragma("unroll") for (int i = 0; i < 2; ++i) af[i] =                 \
        *(const bf16x8*)&As[CB][am[i] + kswz];                            \
    _Pragma("unroll") for (int i = 0; i < 4; ++i) bf[i] =                 \
        *(const bf16x8*)&Bs[CB][bn[i] + kswz];                            \
    _Pragma("unroll") for (int im = 0; im < 2; ++im)                      \
        _Pragma("unroll") for (int in = 0; in < 4; ++in) acc[im][in] =    \
            __builtin_amdgcn_mfma_f32_16x16x32_bf16(af[im], bf[in],       \
                                                    acc[im][in], 0, 0, 0);\
  }

  G2_STAGE(0, 0)
  G2_LOADB(0, dA)
  G2_LOADB(1, dB)
  asm volatile("s_waitcnt vmcnt(4)" ::: "memory");  // A(0)+B(0) done
  FENCE();
  G2_WRITEB(0, dA)
  asm volatile("s_waitcnt lgkmcnt(0)" ::: "memory");
  FENCE();
  __builtin_amdgcn_s_barrier();
  FENCE();

  int cur = 0;
#pragma unroll 1
  for (int t2 = 0; t2 < 7; ++t2) {
    const int t = t2 * 2;
    G2_STAGE(cur ^ 1, t + 1)
    G2_LOADB(t + 2, dA)
    G2_COMPUTE(cur)
    asm volatile("s_waitcnt vmcnt(8)" ::: "memory");  // B(t+1) regs ready
    FENCE();
    G2_WRITEB(cur ^ 1, dB)
    asm volatile("s_waitcnt vmcnt(4) lgkmcnt(0)" ::: "memory");  // A(t+1) in
    FENCE();
    __builtin_amdgcn_s_barrier();
    FENCE();
    cur ^= 1;
    G2_STAGE(cur ^ 1, t + 2)
    G2_LOADB(t + 3, dB)
    G2_COMPUTE(cur)
    asm volatile("s_waitcnt vmcnt(8)" ::: "memory");
    FENCE();
    G2_WRITEB(cur ^ 1, dA)
    asm volatile("s_waitcnt vmcnt(4) lgkmcnt(0)" ::: "memory");
    FENCE();
    __builtin_amdgcn_s_barrier();
    FENCE();
    cur ^= 1;
  }
  G2_STAGE(cur ^ 1, 15)
  G2_COMPUTE(cur)
  asm volatile("s_waitcnt vmcnt(4)" ::: "memory");  // B(15) done, A(15) left
  FENCE();
  G2_WRITEB(cur ^ 1, dB)
  asm volatile("s_waitcnt vmcnt(0) lgkmcnt(0)" ::: "memory");
  FENCE();
  __builtin_amdgcn_s_barrier();
  FENCE();
  cur ^= 1;
  G2_COMPUTE(cur)

#pragma unroll
  for (int im = 0; im < 2; ++im) {
#pragma unroll
    for (int r = 0; r < 4; ++r) {
      const int row = wm + im * 16 + lq * 4 + r;
      const int slot = m0 + row;
      if (slot < count) {
        float* orow = obuf + (size_t)(off_e + slot) * H_DIM + n0;
#pragma unroll
        for (int in = 0; in < 4; ++in)
          orow[in * 16 + lc] = acc[im][in][r];  // plain store, no atomics
      }
    }
  }
}

// ---------------------------------------------------------------------------
// Kernel 5: combine — out[t] = obuf[row(t,0)] + obuf[row(t,1)].
// Fully overwrites out (memset(out) dropped). 2048 blocks x 256 thr, float4.
// ---------------------------------------------------------------------------
__global__ __launch_bounds__(256) void combine_kernel(
    const float* __restrict__ obuf, const int* __restrict__ rows,
    const int* __restrict__ offsets, float* __restrict__ out) {
  const int t = blockIdx.x;
  const int c = threadIdx.x * 4;
  const int e0 = rows[t * 2 + 0];
  const int e1 = rows[t * 2 + 1];
  const size_t r0 = offsets[e0 >> 12] + (e0 & 4095);
  const size_t r1 = offsets[e1 >> 12] + (e1 & 4095);
  const float4 a = *(const float4*)(obuf + r0 * H_DIM + c);
  const float4 b = *(const float4*)(obuf + r1 * H_DIM + c);
  float4 o;
  o.x = a.x + b.x;
  o.y = a.y + b.y;
  o.z = a.z + b.z;
  o.w = a.w + b.w;
  *(float4*)(out + (size_t)t * H_DIM + c) = o;
}

// ---------------------------------------------------------------------------
extern "C" void kernel_launch(void* const* d_in, const int* in_sizes, int n_in,
                              void* d_out, int out_size, void* d_ws,
                              size_t ws_size, hipStream_t stream) {
  const float* x = (const float*)d_in[0];
  const float* rw = (const float*)d_in[1];
  const float* gate = (const float*)d_in[2];
  const float* up = (const float*)d_in[3];
  const float* down = (const float*)d_in[4];
  float* out = (float*)d_out;

  uint8_t* ws = (uint8_t*)d_ws;
  int* counts = (int*)(ws + WS_COUNTS);
  int* offsets = (int*)(ws + WS_OFFSETS);
  int* rows = (int*)(ws + WS_ROWS);
  int* tokens = (int*)(ws + WS_TOKENS);
  float* wts = (float*)(ws + WS_WTS);
  uint16_t* xbf = (uint16_t*)(ws + WS_XBF);
  uint16_t* hbuf = (uint16_t*)(ws + WS_HBUF);
  float* obuf = (float*)(ws + WS_OBUF);

  hipMemsetAsync(counts, 0, 2048, stream);

  router_kernel<<<512, 256, 0, stream>>>(x, rw, xbf, counts, tokens, wts,
                                         rows);
  offsets_kernel<<<1, 64, 0, stream>>>(counts, offsets);
  gemm1_kernel<<<dim3(16, 16, 16), 256, 0, stream>>>(
      xbf, gate, up, counts, offsets, tokens, wts, hbuf);
  gemm2_kernel<<<dim3(16, 16, 16), 256, 0, stream>>>(hbuf, down, counts,
                                                     offsets, obuf);
  combine_kernel<<<T_TOK, 256, 0, stream>>>(obuf, rows, offsets, out);
}